// Round 20
// baseline (60.368 us; speedup 1.0000x reference)
//
#include <hip/hip_runtime.h>
#include <hip/hip_bf16.h>

typedef __bf16 bf16x8 __attribute__((ext_vector_type(8)));
typedef float  f32x4  __attribute__((ext_vector_type(4)));

#define B_ROWS 8192
#define IN_DIM 256
#define OUT_DIM 32
#define NCLS 50
#define INV_T (1.0f / 0.6f)

#define CVT_BLOCKS 1024  // x cvt: 8192*256 / (256*8)
#define ROWTILES 16      // 8192 / 512 rows per block
#define OSTRIDE (NCLS * OUT_DIM)

__device__ __forceinline__ void gload_lds16(const void* g, void* l) {
    __builtin_amdgcn_global_load_lds(
        (const __attribute__((address_space(1))) void*)g,
        (__attribute__((address_space(3))) void*)l, 16, 0, 0);
}

// prep (r14 verbatim): blocks [0,50) W-class; blocks [50,1074) x cvt.
__global__ __launch_bounds__(256) void prep(const float* __restrict__ x,
                                            const float* __restrict__ w,
                                            __bf16* __restrict__ xb,
                                            __bf16* __restrict__ wb) {
    __shared__ float wm[4];
    int bid = blockIdx.x;
    if (bid < NCLS) {
        int c = bid;
        int i = threadIdx.x;
        const float* wc = w + (size_t)c * OUT_DIM * IN_DIM + i;
        float wv[OUT_DIM];
#pragma unroll
        for (int o = 0; o < OUT_DIM; ++o) wv[o] = wc[o * IN_DIM];
        float gsum = 0.f;
#pragma unroll
        for (int o = 0; o < OUT_DIM; ++o) gsum += fabsf(wv[o]);
        float m = gsum;
#pragma unroll
        for (int s = 1; s < 64; s <<= 1) m = fmaxf(m, __shfl_xor(m, s));
        if ((threadIdx.x & 63) == 0) wm[threadIdx.x >> 6] = m;
        __syncthreads();
        m = fmaxf(fmaxf(wm[0], wm[1]), fmaxf(wm[2], wm[3]));
        float an = __expf((gsum - m) * INV_T);
        __bf16* wo = wb + (size_t)c * OUT_DIM * IN_DIM + i;
#pragma unroll
        for (int o = 0; o < OUT_DIM; ++o)
            wo[o * IN_DIM] = (__bf16)(wv[o] * an);
    } else {
        int i = ((bid - NCLS) * 256 + threadIdx.x) * 8;
        float4 v0 = *reinterpret_cast<const float4*>(x + i);
        float4 v1 = *reinterpret_cast<const float4*>(x + i + 4);
        bf16x8 r;
        r[0] = (__bf16)v0.x; r[1] = (__bf16)v0.y; r[2] = (__bf16)v0.z; r[3] = (__bf16)v0.w;
        r[4] = (__bf16)v1.x; r[5] = (__bf16)v1.y; r[6] = (__bf16)v1.z; r[7] = (__bf16)v1.w;
        *reinterpret_cast<bf16x8*>(xb + i) = r;
    }
}

// GEMM — high-TLP variant: out[b,c,o] = sum_i xb[b,i]*wb[c,o,i] + bias[c,o]
// grid = 50 classes * 16 row-tiles (bid = c*16+rt -> rt fixes XCD -> xb slice
// L2-resident). Block = 4 waves, 512 rows, ONE class; wave = 128 rows =
// 8 chunks = 16 half-K halves. Buffers: 2 x 4KB per wave (LDS 32 KB/block ->
// 5 blocks/CU = 20 waves/CU). Prefetch distance 1; TLP (5 waves/SIMD) hides
// staging latency. W' (16 KB) staged into the Abuf1 union, 64 pinned VGPRs.
// vmcnt (4 loads/iter, 2 stores after odd h): h=0:4, odd:4, even>=2:6, 15:0.
// Swizzles (both-sides): A 256B rows, phys slot p15 holds logical p15^(rr&15);
// W 512B rows, phys s31 holds logical s31^(r&15).
__global__ __launch_bounds__(256, 5) void gemm(const __bf16* __restrict__ xb,
                                               const __bf16* __restrict__ wb,
                                               const float* __restrict__ bias,
                                               float* __restrict__ out) {
    __shared__ __align__(16) char lds[4 * 8192];  // per wave: buf0(4K) + buf1(4K)

    int bid = blockIdx.x;
    int c = bid >> 4;            // 0..49
    int rt = bid & (ROWTILES - 1);
    int row0 = rt * 512;
    int lane = threadIdx.x & 63;
    int w4 = threadIdx.x >> 6;
    int l15 = lane & 15;
    int g = lane >> 4;
    int s31 = lane & 31;
    int lr = lane >> 5;
    int r4 = lane >> 4;          // A-stage row-in-group

    char* buf0 = lds + w4 * 8192;
    char* buf1 = buf0 + 4096;

    const char* arows = (const char*)(xb + (size_t)(row0 + w4 * 128) * IN_DIM);

    // stage half H (16 rows x 128 K = 4 KB): 4 instrs; instr j covers rows
    // (H>>1)*16 + j*4 + r4, K-half (H&1). dst row-major [4][16] slots.
#define STAGE_H(BUF, H)                                                            \
    _Pragma("unroll") for (int j = 0; j < 4; ++j) {                                \
        int rr = ((H) >> 1) * 16 + j * 4 + r4;                                     \
        gload_lds16(arows + (size_t)rr * 512 + ((H) & 1) * 256                     \
                        + ((l15 ^ (rr & 15)) * 16),                                \
                    (BUF) + j * 1024);                                             \
    }

    STAGE_H(buf0, 0)

    // --- stage W' (16 KB = 32 rows x 512 B) into the 4 waves' buf1 union ---
    // W row r -> region r>>3 (wave), offset (r&7)*512
    const char* wsrc = (const char*)(wb + (size_t)c * OUT_DIM * IN_DIM);
#pragma unroll
    for (int j = 0; j < 4; ++j) {
        int re = w4 * 8 + 2 * j;
        int r = re + lr;
        gload_lds16(wsrc + (size_t)r * 512 + ((s31 ^ (r & 15)) * 16),
                    lds + w4 * 8192 + 4096 + (re & 7) * 512);
    }

    asm volatile("s_waitcnt vmcnt(0)" ::: "memory");
    __syncthreads();
    __builtin_amdgcn_sched_barrier(0);

    // --- W' -> 64 pinned VGPRs: W[kk] o=l15, W[8+kk] o=16+l15 ---
    bf16x8 W[16];
#pragma unroll
    for (int kk = 0; kk < 8; ++kk) {
        int wr1 = l15;
        int wr2 = 16 + l15;
        W[kk]     = *reinterpret_cast<const bf16x8*>(
            lds + (wr1 >> 3) * 8192 + 4096 + (wr1 & 7) * 512 + (((4 * kk + g) ^ l15) * 16));
        W[8 + kk] = *reinterpret_cast<const bf16x8*>(
            lds + (wr2 >> 3) * 8192 + 4096 + (wr2 & 7) * 512 + (((4 * kk + g) ^ l15) * 16));
    }
#pragma unroll
    for (int kk = 0; kk < 16; ++kk)
        asm volatile("" : "+v"(W[kk]));
    __builtin_amdgcn_sched_barrier(0);
    __syncthreads();             // all waves done reading W before half 1 lands

    STAGE_H(buf1, 1)

    f32x4 bv0 = *reinterpret_cast<const f32x4*>(bias + c * OUT_DIM + g * 4);
    f32x4 bv1 = *reinterpret_cast<const f32x4*>(bias + c * OUT_DIM + 16 + g * 4);

    float* orow = out + (size_t)(row0 + w4 * 128 + l15) * OSTRIDE + c * OUT_DIM + g * 4;

    f32x4 acc0, acc1;
#pragma unroll
    for (int h = 0; h < 16; ++h) {
        if (h >= 1 && h <= 14) {
            char* nbuf = (h & 1) ? buf0 : buf1;   // buffer of half h+1
            STAGE_H(nbuf, h + 1)
        }
        if (h == 0)           asm volatile("s_waitcnt vmcnt(4)" ::: "memory");
        else if (h == 15)     asm volatile("s_waitcnt vmcnt(0)" ::: "memory");
        else if (h & 1)       asm volatile("s_waitcnt vmcnt(4)" ::: "memory");
        else                  asm volatile("s_waitcnt vmcnt(6)" ::: "memory");
        __builtin_amdgcn_sched_barrier(0);

        if (!(h & 1)) { acc0 = bv0; acc1 = bv1; }
        const char* cb = (h & 1) ? buf1 : buf0;
        int h4 = (h & 1) * 4;
#pragma unroll
        for (int kkl = 0; kkl < 4; ++kkl) {
            bf16x8 a = *reinterpret_cast<const bf16x8*>(
                cb + (size_t)l15 * 256 + (((4 * kkl + g) ^ l15) * 16));
            acc0 = __builtin_amdgcn_mfma_f32_16x16x32_bf16(W[h4 + kkl],     a, acc0, 0, 0, 0);
            acc1 = __builtin_amdgcn_mfma_f32_16x16x32_bf16(W[8 + h4 + kkl], a, acc1, 0, 0, 0);
        }
        if (h & 1) {
            float* op = orow + (size_t)(h >> 1) * 16 * OSTRIDE;
            *reinterpret_cast<f32x4*>(op) = acc0;
            *reinterpret_cast<f32x4*>(op + 16) = acc1;
        }
    }
#undef STAGE_H
}

extern "C" void kernel_launch(void* const* d_in, const int* in_sizes, int n_in,
                              void* d_out, int out_size, void* d_ws, size_t ws_size,
                              hipStream_t stream) {
    const float* x    = (const float*)d_in[0];
    const float* w    = (const float*)d_in[1];
    const float* bias = (const float*)d_in[2];
    float* out = (float*)d_out;

    __bf16* xb = (__bf16*)d_ws;                      // 8192*256 bf16 = 4 MB
    __bf16* wb = xb + (size_t)B_ROWS * IN_DIM;       // 50*32*256 bf16 = 0.8 MB

    prep<<<NCLS + CVT_BLOCKS, 256, 0, stream>>>(x, w, xb, wb);
    gemm<<<NCLS * ROWTILES, 256, 0, stream>>>(xb, wb, bias, out);
}